// Round 1
// baseline (327.850 us; speedup 1.0000x reference)
//
#include <hip/hip_runtime.h>
#include <hip/hip_bf16.h>
#include <math.h>

// Problem constants (from reference setup_inputs)
#define BATCH 8
#define SEQ   1536
#define DIM   1024
#define SEQ2  (2*SEQ)          // 3072
#define TEMP_INV 20.0f         // 1 / 0.05

// GEMM tiling
#define BM 128
#define BN 128
#define BK 32

typedef __bf16 bf16x8 __attribute__((ext_vector_type(8)));
typedef float  f32x4  __attribute__((ext_vector_type(4)));

#define GLOBAL_AS __attribute__((address_space(1)))
#define LDS_AS    __attribute__((address_space(3)))

__device__ inline void async_ld16(const void* g, void* lds_uniform) {
    // gfx950: direct global->LDS, 16B per lane; LDS dest = wave-uniform base + lane*16
    __builtin_amdgcn_global_load_lds((const GLOBAL_AS void*)g, (LDS_AS void*)lds_uniform, 16, 0, 0);
}

__device__ inline float wave_red64(float v) {
    #pragma unroll
    for (int m = 32; m > 0; m >>= 1) v += __shfl_xor(v, m, 64);
    return v;
}

// ---------------------------------------------------------------------------
// Kernel 1: L2-normalize both views, write bf16 feats [B][2S][D], and the
// positive-pair cosine per token (fp32, computed pre-bf16 for accuracy).
// One block (256 thr) per token pair; each thread owns 4 consecutive floats.
// ---------------------------------------------------------------------------
__global__ __launch_bounds__(256) void normalize_kernel(
        const float* __restrict__ h1, const float* __restrict__ h2,
        __hip_bfloat16* __restrict__ feats, float* __restrict__ pos_cos) {
    int tok = blockIdx.x;            // 0 .. B*S-1
    int b = tok / SEQ, s = tok - b * SEQ;
    int t = threadIdx.x;

    const float4* a4 = (const float4*)(h1 + (size_t)tok * DIM);
    const float4* b4 = (const float4*)(h2 + (size_t)tok * DIM);
    float4 av = a4[t], bv = b4[t];

    float ss1 = av.x*av.x + av.y*av.y + av.z*av.z + av.w*av.w;
    float ss2 = bv.x*bv.x + bv.y*bv.y + bv.z*bv.z + bv.w*bv.w;
    float sd  = av.x*bv.x + av.y*bv.y + av.z*bv.z + av.w*bv.w;

    ss1 = wave_red64(ss1); ss2 = wave_red64(ss2); sd = wave_red64(sd);

    __shared__ float r1[4], r2[4], rd[4];
    int lane = t & 63, w = t >> 6;
    if (lane == 0) { r1[w] = ss1; r2[w] = ss2; rd[w] = sd; }
    __syncthreads();
    float S1 = r1[0]+r1[1]+r1[2]+r1[3];
    float S2v = r2[0]+r2[1]+r2[2]+r2[3];
    float SD = rd[0]+rd[1]+rd[2]+rd[3];

    float sc1 = 1.0f / fmaxf(sqrtf(S1), 1e-12f);
    float sc2 = 1.0f / fmaxf(sqrtf(S2v), 1e-12f);

    __hip_bfloat16* f1row = feats + ((size_t)b * SEQ2 + s) * DIM;
    __hip_bfloat16* f2row = feats + ((size_t)b * SEQ2 + SEQ + s) * DIM;

    ushort4 o1, o2;
    o1.x = __bfloat16_as_ushort(__float2bfloat16(av.x * sc1));
    o1.y = __bfloat16_as_ushort(__float2bfloat16(av.y * sc1));
    o1.z = __bfloat16_as_ushort(__float2bfloat16(av.z * sc1));
    o1.w = __bfloat16_as_ushort(__float2bfloat16(av.w * sc1));
    o2.x = __bfloat16_as_ushort(__float2bfloat16(bv.x * sc2));
    o2.y = __bfloat16_as_ushort(__float2bfloat16(bv.y * sc2));
    o2.z = __bfloat16_as_ushort(__float2bfloat16(bv.z * sc2));
    o2.w = __bfloat16_as_ushort(__float2bfloat16(bv.w * sc2));
    ((ushort4*)f1row)[t] = o1;
    ((ushort4*)f2row)[t] = o2;

    if (t == 0) pos_cos[tok] = SD * sc1 * sc2;
}

// ---------------------------------------------------------------------------
// Kernel 2: fused sim-GEMM + exp + neg-mask + row-sum into Ng[b][2S].
// m97-style: 128x128 C tile, 4 waves in 2x2, 16x16x32 bf16 MFMA, BK=32,
// global_load_lds(16B) staging, unpadded row-major LDS tiles.
// ---------------------------------------------------------------------------
__global__ __launch_bounds__(256) void gemm_ng_kernel(
        const __hip_bfloat16* __restrict__ feats, const int* __restrict__ mask,
        float* __restrict__ Ng) {
    int b = blockIdx.z;
    int ibase = blockIdx.y * BM;     // rows (i tokens)
    int jbase = blockIdx.x * BN;     // cols (j tokens)
    const __hip_bfloat16* fb = feats + (size_t)b * SEQ2 * DIM;

    __shared__ __align__(16) __hip_bfloat16 As[BM][BK];  // 8 KB
    __shared__ __align__(16) __hip_bfloat16 Bs[BN][BK];  // 8 KB

    int t = threadIdx.x;
    int lane = t & 63, w = t >> 6;
    int wrow = w >> 1, wcol = w & 1;       // 2x2 waves -> 64x64 each
    int colq = lane & 15, quad = lane >> 4;

    // Staging addresses: chunk idx = w*64 + lane (+256 for 2nd issue),
    // row = idx>>2 (4 x 16B chunks per 64B row), part = idx&3.
    int idx = w * 64 + lane;
    int r0 = idx >> 2, p0 = idx & 3;
    const char* asrc0 = (const char*)(fb + (size_t)(ibase + r0) * DIM) + p0 * 16;
    const char* asrc1 = (const char*)(fb + (size_t)(ibase + r0 + 64) * DIM) + p0 * 16;
    const char* bsrc0 = (const char*)(fb + (size_t)(jbase + r0) * DIM) + p0 * 16;
    const char* bsrc1 = (const char*)(fb + (size_t)(jbase + r0 + 64) * DIM) + p0 * 16;
    char* adst0 = (char*)&As[0][0] + w * 1024;          // wave-uniform LDS bases
    char* adst1 = (char*)&As[0][0] + 4096 + w * 1024;
    char* bdst0 = (char*)&Bs[0][0] + w * 1024;
    char* bdst1 = (char*)&Bs[0][0] + 4096 + w * 1024;

    int koff = quad * 8;                    // fragment k offset within BK
    f32x4 acc[4][4] = {};

    for (int k0 = 0; k0 < DIM; k0 += BK) {
        __syncthreads();                    // LDS reuse from previous iter
        size_t kb = (size_t)k0 * 2;         // byte offset along k
        async_ld16(asrc0 + kb, adst0);
        async_ld16(asrc1 + kb, adst1);
        async_ld16(bsrc0 + kb, bdst0);
        async_ld16(bsrc1 + kb, bdst1);
        asm volatile("s_waitcnt vmcnt(0)" ::: "memory");
        __syncthreads();

        bf16x8 af[4], bfr[4];
        #pragma unroll
        for (int mi = 0; mi < 4; mi++)
            af[mi] = *(const bf16x8*)&As[wrow * 64 + mi * 16 + colq][koff];
        #pragma unroll
        for (int nj = 0; nj < 4; nj++)
            bfr[nj] = *(const bf16x8*)&Bs[wcol * 64 + nj * 16 + colq][koff];

        #pragma unroll
        for (int mi = 0; mi < 4; mi++)
            #pragma unroll
            for (int nj = 0; nj < 4; nj++)
                acc[mi][nj] = __builtin_amdgcn_mfma_f32_16x16x32_bf16(
                    af[mi], bfr[nj], acc[mi][nj], 0, 0, 0);
    }

    // Epilogue: val = exp(dot * 20); keep only j with mask[j%S] and j%S != i%S.
    // C/D layout: col = lane&15, row = quad*4 + reg.
    float mj[4]; int jmod[4];
    #pragma unroll
    for (int nj = 0; nj < 4; nj++) {
        int j = jbase + wcol * 64 + nj * 16 + colq;
        int jm = (j < SEQ) ? j : j - SEQ;
        jmod[nj] = jm;
        mj[nj] = mask[b * SEQ + jm] ? 1.0f : 0.0f;
    }
    #pragma unroll
    for (int mi = 0; mi < 4; mi++) {
        float rsum[4] = {0.f, 0.f, 0.f, 0.f};
        #pragma unroll
        for (int nj = 0; nj < 4; nj++) {
            #pragma unroll
            for (int r = 0; r < 4; r++) {
                int i = ibase + wrow * 64 + mi * 16 + quad * 4 + r;
                int im = (i < SEQ) ? i : i - SEQ;
                float v = __expf(acc[mi][nj][r] * TEMP_INV) * mj[nj];
                rsum[r] += (im != jmod[nj]) ? v : 0.0f;
            }
        }
        #pragma unroll
        for (int r = 0; r < 4; r++) {
            float v = rsum[r];
            #pragma unroll
            for (int m = 1; m < 16; m <<= 1) v += __shfl_xor(v, m, 64);
            if (colq == 0) {
                int i = ibase + wrow * 64 + mi * 16 + quad * 4 + r;
                atomicAdd(&Ng[b * SEQ2 + i], v);
            }
        }
    }
}

// ---------------------------------------------------------------------------
// Kernel 3: per-batch masked mean of per-token loss.
// per_tok[i] = log1p(Ng[i] * exp(-pos_sim/T))
// ---------------------------------------------------------------------------
__global__ __launch_bounds__(256) void loss_kernel(
        const float* __restrict__ Ng, const float* __restrict__ pos_cos,
        const int* __restrict__ mask, float* __restrict__ per_sample) {
    int b = blockIdx.x, t = threadIdx.x;
    float sum = 0.f, cnt = 0.f;
    for (int i = t; i < SEQ2; i += 256) {
        int im = (i < SEQ) ? i : i - SEQ;
        if (mask[b * SEQ + im]) {
            float ps = pos_cos[b * SEQ + im] * TEMP_INV;
            float ng = Ng[b * SEQ2 + i];
            sum += log1pf(ng * __expf(-ps));
            cnt += 1.0f;
        }
    }
    sum = wave_red64(sum); cnt = wave_red64(cnt);
    __shared__ float rs[4], rc[4];
    int lane = t & 63, w = t >> 6;
    if (lane == 0) { rs[w] = sum; rc[w] = cnt; }
    __syncthreads();
    if (t == 0) {
        float s = rs[0]+rs[1]+rs[2]+rs[3];
        float c = rc[0]+rc[1]+rc[2]+rc[3];
        per_sample[b] = s / c;
    }
}

__global__ void final_kernel(const float* __restrict__ per_sample, float* __restrict__ out) {
    if (threadIdx.x == 0) {
        float s = 0.f;
        #pragma unroll
        for (int b = 0; b < BATCH; b++) s += per_sample[b];
        out[0] = s / (float)BATCH;
    }
}

// ---------------------------------------------------------------------------
extern "C" void kernel_launch(void* const* d_in, const int* in_sizes, int n_in,
                              void* d_out, int out_size, void* d_ws, size_t ws_size,
                              hipStream_t stream) {
    const float* h1  = (const float*)d_in[0];
    const float* h2  = (const float*)d_in[1];
    const int* mask  = (const int*)d_in[2];
    float* out       = (float*)d_out;

    char* ws = (char*)d_ws;
    size_t feats_bytes = (size_t)BATCH * SEQ2 * DIM * 2;      // 50,331,648
    __hip_bfloat16* feats = (__hip_bfloat16*)ws;
    float* pos_cos    = (float*)(ws + feats_bytes);
    float* Ng         = (float*)(ws + feats_bytes + (size_t)BATCH * SEQ * 4);
    float* per_sample = (float*)(ws + feats_bytes + (size_t)BATCH * SEQ * 4
                                 + (size_t)BATCH * SEQ2 * 4);

    hipMemsetAsync(Ng, 0, (size_t)BATCH * SEQ2 * 4, stream);

    normalize_kernel<<<BATCH * SEQ, 256, 0, stream>>>(h1, h2, feats, pos_cos);

    dim3 g2(SEQ2 / BN, SEQ2 / BM, BATCH);
    gemm_ng_kernel<<<g2, 256, 0, stream>>>(feats, mask, Ng);

    loss_kernel<<<BATCH, 256, 0, stream>>>(Ng, pos_cos, mask, per_sample);
    final_kernel<<<1, 64, 0, stream>>>(per_sample, out);
}

// Round 2
// 266.653 us; speedup vs baseline: 1.2295x; 1.2295x over previous
//
#include <hip/hip_runtime.h>
#include <hip/hip_bf16.h>
#include <math.h>

// Problem constants (from reference setup_inputs)
#define BATCH 8
#define SEQ   1536
#define DIM   1024
#define SEQ2  (2*SEQ)          // 3072
#define TEMP_INV 20.0f         // 1 / 0.05

// GEMM tiling
#define BM 128
#define BN 128
#define BK 32
#define TILES  (SEQ2 / BM)             // 24
#define NPAIRS (TILES * (TILES+1) / 2) // 300 upper-triangular tile pairs

typedef __bf16 bf16x8 __attribute__((ext_vector_type(8)));
typedef float  f32x4  __attribute__((ext_vector_type(4)));

#define GLOBAL_AS __attribute__((address_space(1)))
#define LDS_AS    __attribute__((address_space(3)))

__device__ inline void async_ld16(const void* g, void* lds_uniform) {
    // gfx950: direct global->LDS, 16B/lane; LDS dest = wave-uniform base + lane*16
    __builtin_amdgcn_global_load_lds((const GLOBAL_AS void*)g, (LDS_AS void*)lds_uniform, 16, 0, 0);
}

__device__ inline float wave_red64(float v) {
    #pragma unroll
    for (int m = 32; m > 0; m >>= 1) v += __shfl_xor(v, m, 64);
    return v;
}

// LDS bank swizzle: 16B chunk c of row r is stored at chunk slot c ^ sw(r).
// sw(r) = (r + (r>>2)) & 3 makes every 8-lane b128 issue group cover all 32
// banks for the fragment-read pattern row = base + colq, chunk = quad.
__device__ inline int swz(int r) { return (r + (r >> 2)) & 3; }

// ---------------------------------------------------------------------------
// Kernel 1: L2-normalize both views -> bf16 feats [B][2S][D]; fp32 pos cosine;
// also zero-init Ng (harness poisons ws each call).
// ---------------------------------------------------------------------------
__global__ __launch_bounds__(256) void normalize_kernel(
        const float* __restrict__ h1, const float* __restrict__ h2,
        __hip_bfloat16* __restrict__ feats, float* __restrict__ pos_cos,
        float* __restrict__ Ng) {
    int tok = blockIdx.x;            // 0 .. B*S-1
    int b = tok / SEQ, s = tok - b * SEQ;
    int t = threadIdx.x;

    const float4* a4 = (const float4*)(h1 + (size_t)tok * DIM);
    const float4* b4 = (const float4*)(h2 + (size_t)tok * DIM);
    float4 av = a4[t], bv = b4[t];

    float ss1 = av.x*av.x + av.y*av.y + av.z*av.z + av.w*av.w;
    float ss2 = bv.x*bv.x + bv.y*bv.y + bv.z*bv.z + bv.w*bv.w;
    float sd  = av.x*bv.x + av.y*bv.y + av.z*bv.z + av.w*bv.w;

    ss1 = wave_red64(ss1); ss2 = wave_red64(ss2); sd = wave_red64(sd);

    __shared__ float r1[4], r2[4], rd[4];
    int lane = t & 63, w = t >> 6;
    if (lane == 0) { r1[w] = ss1; r2[w] = ss2; rd[w] = sd; }
    __syncthreads();
    float S1 = r1[0]+r1[1]+r1[2]+r1[3];
    float S2v = r2[0]+r2[1]+r2[2]+r2[3];
    float SD = rd[0]+rd[1]+rd[2]+rd[3];

    float sc1 = 1.0f / fmaxf(sqrtf(S1), 1e-12f);
    float sc2 = 1.0f / fmaxf(sqrtf(S2v), 1e-12f);

    __hip_bfloat16* f1row = feats + ((size_t)b * SEQ2 + s) * DIM;
    __hip_bfloat16* f2row = feats + ((size_t)b * SEQ2 + SEQ + s) * DIM;

    ushort4 o1, o2;
    o1.x = __bfloat16_as_ushort(__float2bfloat16(av.x * sc1));
    o1.y = __bfloat16_as_ushort(__float2bfloat16(av.y * sc1));
    o1.z = __bfloat16_as_ushort(__float2bfloat16(av.z * sc1));
    o1.w = __bfloat16_as_ushort(__float2bfloat16(av.w * sc1));
    o2.x = __bfloat16_as_ushort(__float2bfloat16(bv.x * sc2));
    o2.y = __bfloat16_as_ushort(__float2bfloat16(bv.y * sc2));
    o2.z = __bfloat16_as_ushort(__float2bfloat16(bv.z * sc2));
    o2.w = __bfloat16_as_ushort(__float2bfloat16(bv.w * sc2));
    ((ushort4*)f1row)[t] = o1;
    ((ushort4*)f2row)[t] = o2;

    if (t == 0) {
        pos_cos[tok] = SD * sc1 * sc2;
        Ng[2*tok] = 0.0f;       // B*S blocks x2 = B*SEQ2 entries covered
        Ng[2*tok + 1] = 0.0f;
    }
}

// ---------------------------------------------------------------------------
// Kernel 2: symmetric fused sim-GEMM + exp + neg-mask.
// Only upper-triangular tile pairs (ti<=tj); off-diag tiles accumulate BOTH
// row sums (-> Ng[i]) and col sums (-> Ng[j]) since sim is symmetric.
// 128x128 tile, 2x2 waves of 64x64, 16x16x32 bf16 MFMA, BK=32,
// global_load_lds(16B) with bank-conflict-free chunk swizzle.
// ---------------------------------------------------------------------------
__global__ __launch_bounds__(256) void gemm_ng_kernel(
        const __hip_bfloat16* __restrict__ feats, const int* __restrict__ mask,
        float* __restrict__ Ng) {
    int b = blockIdx.z;
    // decode triangular pair index -> (ti, tj), ti <= tj
    int p = blockIdx.x;
    int ti = 0;
    while (p >= TILES - ti) { p -= TILES - ti; ti++; }
    int tj = ti + p;
    int ibase = ti * BM, jbase = tj * BN;
    bool isdiag = (ti == tj);

    const __hip_bfloat16* fb = feats + (size_t)b * SEQ2 * DIM;

    __shared__ __align__(16) __hip_bfloat16 As[BM][BK];  // 8 KB (swizzled chunks)
    __shared__ __align__(16) __hip_bfloat16 Bs[BN][BK];  // 8 KB
    __shared__ float mrow_s[BM];
    __shared__ float mcol_s[BN];

    int t = threadIdx.x;
    int lane = t & 63, w = t >> 6;
    int wrow = w >> 1, wcol = w & 1;       // 2x2 waves -> 64x64 each
    int colq = lane & 15, quad = lane >> 4;

    // stage masks (as float) for the tile's rows/cols
    if (t < BM) {
        int i = ibase + t; int im = (i < SEQ) ? i : i - SEQ;
        mrow_s[t] = mask[b * SEQ + im] ? 1.0f : 0.0f;
    } else {
        int j = jbase + (t - BM); int jm = (j < SEQ) ? j : j - SEQ;
        mcol_s[t - BM] = mask[b * SEQ + jm] ? 1.0f : 0.0f;
    }

    // Staging: slot idx = w*64+lane holds row r0 = idx>>2, stored chunk idx&3,
    // i.e. LOGICAL chunk p0 = (idx&3) ^ swz(r0).  swz(r0+64) == swz(r0).
    int idx = w * 64 + lane;
    int r0 = idx >> 2;
    int p0 = (idx & 3) ^ swz(r0);
    const char* asrc0 = (const char*)(fb + (size_t)(ibase + r0) * DIM) + p0 * 16;
    const char* asrc1 = (const char*)(fb + (size_t)(ibase + r0 + 64) * DIM) + p0 * 16;
    const char* bsrc0 = (const char*)(fb + (size_t)(jbase + r0) * DIM) + p0 * 16;
    const char* bsrc1 = (const char*)(fb + (size_t)(jbase + r0 + 64) * DIM) + p0 * 16;
    char* adst0 = (char*)&As[0][0] + w * 1024;          // wave-uniform LDS bases
    char* adst1 = (char*)&As[0][0] + 4096 + w * 1024;
    char* bdst0 = (char*)&Bs[0][0] + w * 1024;
    char* bdst1 = (char*)&Bs[0][0] + 4096 + w * 1024;

    f32x4 acc[4][4] = {};

    for (int k0 = 0; k0 < DIM; k0 += BK) {
        __syncthreads();                    // LDS reuse from previous iter
        size_t kb = (size_t)k0 * 2;         // byte offset along k
        async_ld16(asrc0 + kb, adst0);
        async_ld16(asrc1 + kb, adst1);
        async_ld16(bsrc0 + kb, bdst0);
        async_ld16(bsrc1 + kb, bdst1);
        asm volatile("s_waitcnt vmcnt(0)" ::: "memory");
        __syncthreads();

        bf16x8 af[4], bfr[4];
        #pragma unroll
        for (int mi = 0; mi < 4; mi++) {
            int row = wrow * 64 + mi * 16 + colq;
            af[mi] = *(const bf16x8*)&As[row][(quad ^ swz(row)) * 8];
        }
        #pragma unroll
        for (int nj = 0; nj < 4; nj++) {
            int row = wcol * 64 + nj * 16 + colq;
            bfr[nj] = *(const bf16x8*)&Bs[row][(quad ^ swz(row)) * 8];
        }

        #pragma unroll
        for (int mi = 0; mi < 4; mi++)
            #pragma unroll
            for (int nj = 0; nj < 4; nj++)
                acc[mi][nj] = __builtin_amdgcn_mfma_f32_16x16x32_bf16(
                    af[mi], bfr[nj], acc[mi][nj], 0, 0, 0);
    }

    // Epilogue.  C/D layout: col = colq, row = quad*4 + reg.
    // e = exp(20*sim) zeroed on same-token; row sums weight by mask[j],
    // col sums (off-diag tiles only) weight by mask[i].
    float mj[4]; int jglob[4];
    #pragma unroll
    for (int nj = 0; nj < 4; nj++) {
        int jl = wcol * 64 + nj * 16 + colq;
        mj[nj] = mcol_s[jl];
        jglob[nj] = jbase + jl;
    }
    float colsum[4] = {0.f, 0.f, 0.f, 0.f};

    #pragma unroll
    for (int mi = 0; mi < 4; mi++) {
        int il0 = wrow * 64 + mi * 16 + quad * 4;   // local row of reg 0
        float rsum[4] = {0.f, 0.f, 0.f, 0.f};
        float mr[4];
        #pragma unroll
        for (int r = 0; r < 4; r++) mr[r] = mrow_s[il0 + r];
        #pragma unroll
        for (int nj = 0; nj < 4; nj++) {
            #pragma unroll
            for (int r = 0; r < 4; r++) {
                int d = (ibase + il0 + r) - jglob[nj];
                bool same = (d == 0) | (d == SEQ) | (d == -SEQ);
                float e = same ? 0.0f : __expf(acc[mi][nj][r] * TEMP_INV);
                rsum[r] += e * mj[nj];
                colsum[nj] += e * mr[r];
            }
        }
        // reduce each row sum across the 16 column lanes (xor 1,2,4,8)
        #pragma unroll
        for (int r = 0; r < 4; r++) {
            float v = rsum[r];
            #pragma unroll
            for (int m = 1; m < 16; m <<= 1) v += __shfl_xor(v, m, 64);
            if (colq == 0)
                atomicAdd(&Ng[b * SEQ2 + ibase + il0 + r], v);
        }
    }

    if (!isdiag) {
        // reduce col sums across the 4 quads (xor 16, 32)
        #pragma unroll
        for (int nj = 0; nj < 4; nj++) {
            float v = colsum[nj];
            v += __shfl_xor(v, 16, 64);
            v += __shfl_xor(v, 32, 64);
            if (quad == 0)
                atomicAdd(&Ng[b * SEQ2 + jglob[nj]], v);
        }
    }
}

// ---------------------------------------------------------------------------
// Kernel 3: per-batch masked mean of per-token loss.
// per_tok[i] = log1p(Ng[i] * exp(-pos_sim/T))
// ---------------------------------------------------------------------------
__global__ __launch_bounds__(256) void loss_kernel(
        const float* __restrict__ Ng, const float* __restrict__ pos_cos,
        const int* __restrict__ mask, float* __restrict__ per_sample) {
    int b = blockIdx.x, t = threadIdx.x;
    float sum = 0.f, cnt = 0.f;
    for (int i = t; i < SEQ2; i += 256) {
        int im = (i < SEQ) ? i : i - SEQ;
        if (mask[b * SEQ + im]) {
            float ps = pos_cos[b * SEQ + im] * TEMP_INV;
            float ng = Ng[b * SEQ2 + i];
            sum += log1pf(ng * __expf(-ps));
            cnt += 1.0f;
        }
    }
    sum = wave_red64(sum); cnt = wave_red64(cnt);
    __shared__ float rs[4], rc[4];
    int lane = t & 63, w = t >> 6;
    if (lane == 0) { rs[w] = sum; rc[w] = cnt; }
    __syncthreads();
    if (t == 0) {
        float s = rs[0]+rs[1]+rs[2]+rs[3];
        float c = rc[0]+rc[1]+rc[2]+rc[3];
        per_sample[b] = s / c;
    }
}

__global__ void final_kernel(const float* __restrict__ per_sample, float* __restrict__ out) {
    if (threadIdx.x == 0) {
        float s = 0.f;
        #pragma unroll
        for (int b = 0; b < BATCH; b++) s += per_sample[b];
        out[0] = s / (float)BATCH;
    }
}

// ---------------------------------------------------------------------------
extern "C" void kernel_launch(void* const* d_in, const int* in_sizes, int n_in,
                              void* d_out, int out_size, void* d_ws, size_t ws_size,
                              hipStream_t stream) {
    const float* h1  = (const float*)d_in[0];
    const float* h2  = (const float*)d_in[1];
    const int* mask  = (const int*)d_in[2];
    float* out       = (float*)d_out;

    char* ws = (char*)d_ws;
    size_t feats_bytes = (size_t)BATCH * SEQ2 * DIM * 2;      // 50,331,648
    __hip_bfloat16* feats = (__hip_bfloat16*)ws;
    float* pos_cos    = (float*)(ws + feats_bytes);
    float* Ng         = (float*)(ws + feats_bytes + (size_t)BATCH * SEQ * 4);
    float* per_sample = (float*)(ws + feats_bytes + (size_t)BATCH * SEQ * 4
                                 + (size_t)BATCH * SEQ2 * 4);

    normalize_kernel<<<BATCH * SEQ, 256, 0, stream>>>(h1, h2, feats, pos_cos, Ng);

    dim3 g2(NPAIRS, 1, BATCH);
    gemm_ng_kernel<<<g2, 256, 0, stream>>>(feats, mask, Ng);

    loss_kernel<<<BATCH, 256, 0, stream>>>(Ng, pos_cos, mask, per_sample);
    final_kernel<<<1, 64, 0, stream>>>(per_sample, out);
}